// Round 3
// baseline (1649.553 us; speedup 1.0000x reference)
//
#include <hip/hip_runtime.h>
#include <hip/hip_bf16.h>

// Problem constants (fixed by the reference setup)
#define N_VERTS   100000
#define N_HGE     10000
#define N_INC     1600000
#define N_EDGES   1600000
#define C_IN      256
#define C_MID     128
#define C_OUT     64
#define NEG       0.2f

// ---------------------------------------------------------------------------
// MLP: h = leaky_relu(x @ W1 + b1) @ W2 + b2   (all f32)
// 16 vertices per block, 256 threads (4 waves).
// Layer1: thread t -> out channel j=t&127, vert group (t>>7)*8 .. +7
// Layer2: thread t -> out channel j=t&63,  vert group (t>>6)*4 .. +3
// Vert-group is wave-uniform -> LDS reads of xs/mid broadcast (no conflicts).
// ---------------------------------------------------------------------------
#define VPB 16
__global__ __launch_bounds__(256) void
mlp_kernel(const float* __restrict__ x, const float* __restrict__ W1,
           const float* __restrict__ b1, const float* __restrict__ W2,
           const float* __restrict__ b2, float* __restrict__ h) {
    __shared__ float xs[VPB][C_IN];
    __shared__ float mid[VPB][C_MID];
    const int t  = threadIdx.x;
    const int v0 = blockIdx.x * VPB;

    // stage 16 x-rows (coalesced: thread t reads column t of each row)
    const float* xp = x + (size_t)v0 * C_IN;
#pragma unroll
    for (int r = 0; r < VPB; ++r)
        xs[r][t] = xp[(size_t)r * C_IN + t];
    __syncthreads();

    {   // layer 1: 16 verts x 128 outputs = 2048; 8 verts per thread
        const int j  = t & 127;
        const int ug = (t >> 7) * 8;
        float acc[8];
        const float bias = b1[j];
#pragma unroll
        for (int i = 0; i < 8; ++i) acc[i] = bias;
        for (int k = 0; k < C_IN; ++k) {
            const float wv = W1[k * C_MID + j];
#pragma unroll
            for (int i = 0; i < 8; ++i)
                acc[i] += xs[ug + i][k] * wv;
        }
#pragma unroll
        for (int i = 0; i < 8; ++i) {
            const float a = acc[i];
            mid[ug + i][j] = a > 0.f ? a : NEG * a;
        }
    }
    __syncthreads();

    {   // layer 2: 16 verts x 64 outputs = 1024; 4 verts per thread
        const int j  = t & 63;
        const int ug = (t >> 6) * 4;
        float acc[4];
        const float bias = b2[j];
#pragma unroll
        for (int i = 0; i < 4; ++i) acc[i] = bias;
        for (int k = 0; k < C_MID; ++k) {
            const float wv = W2[k * C_OUT + j];
#pragma unroll
            for (int i = 0; i < 4; ++i)
                acc[i] += mid[ug + i][k] * wv;
        }
#pragma unroll
        for (int i = 0; i < 4; ++i)
            h[(size_t)(v0 + ug + i) * C_OUT + j] = acc[i];
    }
}

// ---------------------------------------------------------------------------
// One wave (64 lanes) per (src,dst) pair; lane = channel.
// dst_feat[dst][lane] += src_feat[src][lane];  deg[dst] += 1 (lane 0)
// ---------------------------------------------------------------------------
__global__ void scatter_add_kernel(const int* __restrict__ src_idx,
                                   const int* __restrict__ dst_idx,
                                   const float* __restrict__ src_feat,
                                   float* __restrict__ dst_feat,
                                   float* __restrict__ deg, int n_pairs) {
    const int gtid = blockIdx.x * blockDim.x + threadIdx.x;
    const int wid  = gtid >> 6;
    const int lane = threadIdx.x & 63;
    if (wid >= n_pairs) return;
    const int s = src_idx[wid];
    const int d = dst_idx[wid];
    const float v = src_feat[(size_t)s * C_OUT + lane];
    atomicAdd(&dst_feat[(size_t)d * C_OUT + lane], v);
    if (lane == 0) atomicAdd(&deg[d], 1.0f);
}

// feat[r][c] /= max(deg[r], 1)
__global__ void scale_rows_kernel(float* __restrict__ feat,
                                  const float* __restrict__ deg, int n_rows) {
    const int i = blockIdx.x * blockDim.x + threadIdx.x;
    if (i >= n_rows * C_OUT) return;
    const int r = i >> 6;
    feat[i] = feat[i] / fmaxf(deg[r], 1.0f);
}

// out = leaky( sw0 * 0.5*(x_g/deg_g + x_hg/deg_hg) + sw1 * h )  -> f32
__global__ void finalize_kernel(const float* __restrict__ h,
                                const float* __restrict__ x_hg_sum,
                                const float* __restrict__ deg_hg,
                                const float* __restrict__ x_g_sum,
                                const float* __restrict__ deg_g,
                                const float* __restrict__ w,
                                float* __restrict__ out) {
    const int i = blockIdx.x * blockDim.x + threadIdx.x;
    if (i >= N_VERTS * C_OUT) return;
    const int v = i >> 6;
    const float w0 = w[0], w1 = w[1];
    const float m  = fmaxf(w0, w1);
    const float e0 = __expf(w0 - m), e1 = __expf(w1 - m);
    const float sw0 = e0 / (e0 + e1), sw1 = e1 / (e0 + e1);

    const float xhg = x_hg_sum[i] / fmaxf(deg_hg[v], 1.0f);
    const float xg  = x_g_sum[i]  / fmaxf(deg_g[v], 1.0f);
    const float fuse = 0.5f * (xg + xhg);
    float o = sw0 * fuse + sw1 * h[i];
    o = o > 0.f ? o : NEG * o;
    out[i] = o;
}

// ---------------------------------------------------------------------------
extern "C" void kernel_launch(void* const* d_in, const int* in_sizes, int n_in,
                              void* d_out, int out_size, void* d_ws, size_t ws_size,
                              hipStream_t stream) {
    const float* x    = (const float*)d_in[0];
    const float* W1   = (const float*)d_in[1];
    const float* b1   = (const float*)d_in[2];
    const float* W2   = (const float*)d_in[3];
    const float* b2   = (const float*)d_in[4];
    const float* w    = (const float*)d_in[5];
    const int*  hg_v  = (const int*)d_in[6];
    const int*  hg_e  = (const int*)d_in[7];
    const int*  g_src = (const int*)d_in[8];
    const int*  g_dst = (const int*)d_in[9];
    float* out = (float*)d_out;

    // workspace layout (f32)
    float* h        = (float*)d_ws;                        // N_VERTS*64
    float* e_sum    = h        + (size_t)N_VERTS * C_OUT;  // N_HGE*64   (zeroed)
    float* x_hg_sum = e_sum    + (size_t)N_HGE   * C_OUT;  // N_VERTS*64 (zeroed)
    float* x_g_sum  = x_hg_sum + (size_t)N_VERTS * C_OUT;  // N_VERTS*64 (zeroed)
    float* deg_e    = x_g_sum  + (size_t)N_VERTS * C_OUT;  // N_HGE      (zeroed)
    float* deg_hg   = deg_e    + N_HGE;                    // N_VERTS    (zeroed)
    float* deg_g    = deg_hg   + N_VERTS;                  // N_VERTS    (zeroed)

    const size_t zero_elems = (size_t)N_HGE * C_OUT + 2 * (size_t)N_VERTS * C_OUT
                            + N_HGE + 2 * (size_t)N_VERTS;
    hipMemsetAsync(e_sum, 0, zero_elems * sizeof(float), stream);

    // MLP
    mlp_kernel<<<N_VERTS / VPB, 256, 0, stream>>>(x, W1, b1, W2, b2, h);

    // scatter passes: one wave per pair
    const int scat_blocks = (int)(((size_t)N_INC * 64 + 255) / 256);
    scatter_add_kernel<<<scat_blocks, 256, 0, stream>>>(hg_v, hg_e, h, e_sum, deg_e, N_INC);
    scatter_add_kernel<<<scat_blocks, 256, 0, stream>>>(g_src, g_dst, h, x_g_sum, deg_g, N_EDGES);

    // e_feat = e_sum / deg_e
    scale_rows_kernel<<<(N_HGE * C_OUT + 255) / 256, 256, 0, stream>>>(e_sum, deg_e, N_HGE);

    // e2v
    scatter_add_kernel<<<scat_blocks, 256, 0, stream>>>(hg_e, hg_v, e_sum, x_hg_sum, deg_hg, N_INC);

    // finalize
    finalize_kernel<<<(N_VERTS * C_OUT + 255) / 256, 256, 0, stream>>>(
        h, x_hg_sum, deg_hg, x_g_sum, deg_g, w, out);
}

// Round 4
// 1380.435 us; speedup vs baseline: 1.1950x; 1.1950x over previous
//
#include <hip/hip_runtime.h>
#include <hip/hip_bf16.h>

// Problem constants (fixed by the reference setup)
#define N_VERTS   100000
#define N_HGE     10000
#define N_INC     1600000
#define N_EDGES   1600000
#define C_IN      256
#define C_MID     128
#define C_OUT     64
#define NEG       0.2f

// ---------------------------------------------------------------------------
// MLP: h = leaky_relu(x @ W1 + b1) @ W2 + b2   (all f32)
// 16 vertices per block, 256 threads (4 waves).
// ---------------------------------------------------------------------------
#define VPB 16
__global__ __launch_bounds__(256) void
mlp_kernel(const float* __restrict__ x, const float* __restrict__ W1,
           const float* __restrict__ b1, const float* __restrict__ W2,
           const float* __restrict__ b2, float* __restrict__ h) {
    __shared__ float xs[VPB][C_IN];
    __shared__ float mid[VPB][C_MID];
    const int t  = threadIdx.x;
    const int v0 = blockIdx.x * VPB;

    const float* xp = x + (size_t)v0 * C_IN;
#pragma unroll
    for (int r = 0; r < VPB; ++r)
        xs[r][t] = xp[(size_t)r * C_IN + t];
    __syncthreads();

    {   // layer 1: 16 verts x 128 outputs; 8 verts per thread
        const int j  = t & 127;
        const int ug = (t >> 7) * 8;
        float acc[8];
        const float bias = b1[j];
#pragma unroll
        for (int i = 0; i < 8; ++i) acc[i] = bias;
        for (int k = 0; k < C_IN; ++k) {
            const float wv = W1[k * C_MID + j];
#pragma unroll
            for (int i = 0; i < 8; ++i)
                acc[i] += xs[ug + i][k] * wv;
        }
#pragma unroll
        for (int i = 0; i < 8; ++i) {
            const float a = acc[i];
            mid[ug + i][j] = a > 0.f ? a : NEG * a;
        }
    }
    __syncthreads();

    {   // layer 2: 16 verts x 64 outputs; 4 verts per thread
        const int j  = t & 63;
        const int ug = (t >> 6) * 4;
        float acc[4];
        const float bias = b2[j];
#pragma unroll
        for (int i = 0; i < 4; ++i) acc[i] = bias;
        for (int k = 0; k < C_MID; ++k) {
            const float wv = W2[k * C_OUT + j];
#pragma unroll
            for (int i = 0; i < 4; ++i)
                acc[i] += mid[ug + i][k] * wv;
        }
#pragma unroll
        for (int i = 0; i < 4; ++i)
            h[(size_t)(v0 + ug + i) * C_OUT + j] = acc[i];
    }
}

// ---------------------------------------------------------------------------
// CSR build: count degrees for all three groupings in one pass.
// ---------------------------------------------------------------------------
__global__ void count_kernel(const int* __restrict__ hg_v, const int* __restrict__ hg_e,
                             const int* __restrict__ g_dst,
                             int* __restrict__ deg_e, int* __restrict__ deg_vhg,
                             int* __restrict__ deg_vg) {
    const int i = blockIdx.x * blockDim.x + threadIdx.x;
    if (i >= N_INC) return;
    atomicAdd(&deg_e[hg_e[i]], 1);
    atomicAdd(&deg_vhg[hg_v[i]], 1);
    atomicAdd(&deg_vg[g_dst[i]], 1);
}

// Single-block exclusive prefix scan (n up to ~100K). 1024 threads.
__global__ __launch_bounds__(1024) void
scan_kernel(const int* __restrict__ cnt, int* __restrict__ off, int n) {
    __shared__ int sums[1024];
    const int t = threadIdx.x;
    const int chunk = (n + 1023) / 1024;
    const int lo = t * chunk;
    const int hi = min(lo + chunk, n);
    int s = 0;
    for (int i = lo; i < hi; ++i) s += cnt[i];
    sums[t] = s;
    __syncthreads();
    for (int d = 1; d < 1024; d <<= 1) {
        int v = (t >= d) ? sums[t - d] : 0;
        __syncthreads();
        sums[t] += v;
        __syncthreads();
    }
    int run = (t > 0) ? sums[t - 1] : 0;
    for (int i = lo; i < hi; ++i) { off[i] = run; run += cnt[i]; }
}

// Fill adjacency slots: for each grouping, store the *other* index directly.
__global__ void fill_kernel(const int* __restrict__ hg_v, const int* __restrict__ hg_e,
                            const int* __restrict__ g_src, const int* __restrict__ g_dst,
                            const int* __restrict__ off_e, int* __restrict__ cur_e,
                            int* __restrict__ slot_e,
                            const int* __restrict__ off_vhg, int* __restrict__ cur_vhg,
                            int* __restrict__ slot_vhg,
                            const int* __restrict__ off_vg, int* __restrict__ cur_vg,
                            int* __restrict__ slot_vg) {
    const int i = blockIdx.x * blockDim.x + threadIdx.x;
    if (i >= N_INC) return;
    {   // group by hyperedge, store vertex
        const int d = hg_e[i];
        const int p = off_e[d] + atomicAdd(&cur_e[d], 1);
        slot_e[p] = hg_v[i];
    }
    {   // group by vertex (hypergraph), store hyperedge
        const int d = hg_v[i];
        const int p = off_vhg[d] + atomicAdd(&cur_vhg[d], 1);
        slot_vhg[p] = hg_e[i];
    }
    {   // group by dst vertex (graph), store src vertex
        const int d = g_dst[i];
        const int p = off_vg[d] + atomicAdd(&cur_vg[d], 1);
        slot_vg[p] = g_src[i];
    }
}

// ---------------------------------------------------------------------------
// v2e gather: one wave per hyperedge, lane = channel.
// e_feat[e] = mean over incidence list of h[v].
// ---------------------------------------------------------------------------
__global__ void gather_e_kernel(const int* __restrict__ slot, const int* __restrict__ off,
                                const int* __restrict__ deg, const float* __restrict__ h,
                                float* __restrict__ e_feat) {
    const int wid  = (blockIdx.x * blockDim.x + threadIdx.x) >> 6;
    const int lane = threadIdx.x & 63;
    if (wid >= N_HGE) return;
    const int n    = deg[wid];
    const int base = off[wid];
    float acc = 0.f;
    int j = 0;
    for (; j + 4 <= n; j += 4) {
        const int v0 = slot[base + j + 0];
        const int v1 = slot[base + j + 1];
        const int v2 = slot[base + j + 2];
        const int v3 = slot[base + j + 3];
        const float r0 = h[(size_t)v0 * C_OUT + lane];
        const float r1 = h[(size_t)v1 * C_OUT + lane];
        const float r2 = h[(size_t)v2 * C_OUT + lane];
        const float r3 = h[(size_t)v3 * C_OUT + lane];
        acc += (r0 + r1) + (r2 + r3);
    }
    for (; j < n; ++j)
        acc += h[(size_t)slot[base + j] * C_OUT + lane];
    e_feat[(size_t)wid * C_OUT + lane] = acc / fmaxf((float)n, 1.f);
}

// ---------------------------------------------------------------------------
// Fused per-vertex: x_hg gather (over e_feat) + x_g gather (over h) +
// softmax-weighted fuse + leaky -> out. One wave per vertex, lane = channel.
// ---------------------------------------------------------------------------
__global__ void vertex_out_kernel(const int* __restrict__ slot_vhg,
                                  const int* __restrict__ off_vhg,
                                  const int* __restrict__ deg_vhg,
                                  const int* __restrict__ slot_vg,
                                  const int* __restrict__ off_vg,
                                  const int* __restrict__ deg_vg,
                                  const float* __restrict__ e_feat,
                                  const float* __restrict__ h,
                                  const float* __restrict__ w,
                                  float* __restrict__ out) {
    const int wid  = (blockIdx.x * blockDim.x + threadIdx.x) >> 6;
    const int lane = threadIdx.x & 63;
    if (wid >= N_VERTS) return;

    // x_hg: mean of e_feat over hyperedge list
    float acc_hg = 0.f;
    {
        const int n = deg_vhg[wid];
        const int base = off_vhg[wid];
        int j = 0;
        for (; j + 4 <= n; j += 4) {
            const int e0 = slot_vhg[base + j + 0];
            const int e1 = slot_vhg[base + j + 1];
            const int e2 = slot_vhg[base + j + 2];
            const int e3 = slot_vhg[base + j + 3];
            const float r0 = e_feat[(size_t)e0 * C_OUT + lane];
            const float r1 = e_feat[(size_t)e1 * C_OUT + lane];
            const float r2 = e_feat[(size_t)e2 * C_OUT + lane];
            const float r3 = e_feat[(size_t)e3 * C_OUT + lane];
            acc_hg += (r0 + r1) + (r2 + r3);
        }
        for (; j < n; ++j)
            acc_hg += e_feat[(size_t)slot_vhg[base + j] * C_OUT + lane];
        acc_hg /= fmaxf((float)n, 1.f);
    }

    // x_g: mean of h over graph neighbor list
    float acc_g = 0.f;
    {
        const int n = deg_vg[wid];
        const int base = off_vg[wid];
        int j = 0;
        for (; j + 4 <= n; j += 4) {
            const int v0 = slot_vg[base + j + 0];
            const int v1 = slot_vg[base + j + 1];
            const int v2 = slot_vg[base + j + 2];
            const int v3 = slot_vg[base + j + 3];
            const float r0 = h[(size_t)v0 * C_OUT + lane];
            const float r1 = h[(size_t)v1 * C_OUT + lane];
            const float r2 = h[(size_t)v2 * C_OUT + lane];
            const float r3 = h[(size_t)v3 * C_OUT + lane];
            acc_g += (r0 + r1) + (r2 + r3);
        }
        for (; j < n; ++j)
            acc_g += h[(size_t)slot_vg[base + j] * C_OUT + lane];
        acc_g /= fmaxf((float)n, 1.f);
    }

    const float w0 = w[0], w1 = w[1];
    const float m  = fmaxf(w0, w1);
    const float e0 = __expf(w0 - m), e1 = __expf(w1 - m);
    const float sw0 = e0 / (e0 + e1), sw1 = e1 / (e0 + e1);

    const float hv = h[(size_t)wid * C_OUT + lane];
    float o = sw0 * 0.5f * (acc_g + acc_hg) + sw1 * hv;
    o = o > 0.f ? o : NEG * o;
    out[(size_t)wid * C_OUT + lane] = o;
}

// ---------------------------------------------------------------------------
extern "C" void kernel_launch(void* const* d_in, const int* in_sizes, int n_in,
                              void* d_out, int out_size, void* d_ws, size_t ws_size,
                              hipStream_t stream) {
    const float* x    = (const float*)d_in[0];
    const float* W1   = (const float*)d_in[1];
    const float* b1   = (const float*)d_in[2];
    const float* W2   = (const float*)d_in[3];
    const float* b2   = (const float*)d_in[4];
    const float* w    = (const float*)d_in[5];
    const int*  hg_v  = (const int*)d_in[6];
    const int*  hg_e  = (const int*)d_in[7];
    const int*  g_src = (const int*)d_in[8];
    const int*  g_dst = (const int*)d_in[9];
    float* out = (float*)d_out;

    // workspace layout (all 4-byte elems)
    float* h        = (float*)d_ws;                        // N_VERTS*64
    float* e_feat   = h + (size_t)N_VERTS * C_OUT;         // N_HGE*64
    int*   ibase    = (int*)(e_feat + (size_t)N_HGE * C_OUT);
    // zeroed region: deg_e, cur_e, deg_vhg, cur_vhg, deg_vg, cur_vg
    int* deg_e    = ibase;                 // N_HGE
    int* cur_e    = deg_e   + N_HGE;       // N_HGE
    int* deg_vhg  = cur_e   + N_HGE;       // N_VERTS
    int* cur_vhg  = deg_vhg + N_VERTS;     // N_VERTS
    int* deg_vg   = cur_vhg + N_VERTS;     // N_VERTS
    int* cur_vg   = deg_vg  + N_VERTS;     // N_VERTS
    // not zeroed:
    int* off_e    = cur_vg  + N_VERTS;     // N_HGE
    int* off_vhg  = off_e   + N_HGE;       // N_VERTS
    int* off_vg   = off_vhg + N_VERTS;     // N_VERTS
    int* slot_e   = off_vg  + N_VERTS;     // N_INC
    int* slot_vhg = slot_e  + N_INC;       // N_INC
    int* slot_vg  = slot_vhg + N_INC;      // N_EDGES

    const size_t zero_elems = 2 * (size_t)N_HGE + 4 * (size_t)N_VERTS;
    hipMemsetAsync(ibase, 0, zero_elems * sizeof(int), stream);

    // CSR build
    const int pair_blocks = (N_INC + 255) / 256;
    count_kernel<<<pair_blocks, 256, 0, stream>>>(hg_v, hg_e, g_dst,
                                                  deg_e, deg_vhg, deg_vg);
    scan_kernel<<<1, 1024, 0, stream>>>(deg_e,   off_e,   N_HGE);
    scan_kernel<<<1, 1024, 0, stream>>>(deg_vhg, off_vhg, N_VERTS);
    scan_kernel<<<1, 1024, 0, stream>>>(deg_vg,  off_vg,  N_VERTS);
    fill_kernel<<<pair_blocks, 256, 0, stream>>>(hg_v, hg_e, g_src, g_dst,
                                                 off_e, cur_e, slot_e,
                                                 off_vhg, cur_vhg, slot_vhg,
                                                 off_vg, cur_vg, slot_vg);

    // MLP
    mlp_kernel<<<N_VERTS / VPB, 256, 0, stream>>>(x, W1, b1, W2, b2, h);

    // v2e gather
    const int ge_blocks = (int)(((size_t)N_HGE * 64 + 255) / 256);
    gather_e_kernel<<<ge_blocks, 256, 0, stream>>>(slot_e, off_e, deg_e, h, e_feat);

    // fused e2v + graph gather + finalize
    const int vo_blocks = (int)(((size_t)N_VERTS * 64 + 255) / 256);
    vertex_out_kernel<<<vo_blocks, 256, 0, stream>>>(slot_vhg, off_vhg, deg_vhg,
                                                     slot_vg, off_vg, deg_vg,
                                                     e_feat, h, w, out);
}

// Round 5
// 1123.331 us; speedup vs baseline: 1.4684x; 1.2289x over previous
//
#include <hip/hip_runtime.h>
#include <hip/hip_bf16.h>

// Problem constants (fixed by the reference setup)
#define N_VERTS   100000
#define N_HGE     10000
#define N_INC     1600000
#define N_EDGES   1600000
#define C_IN      256
#define C_MID     128
#define C_OUT     64
#define NEG       0.2f

// ---------------------------------------------------------------------------
// MLP: h = leaky_relu(x @ W1 + b1) @ W2 + b2   (all f32)
// 32 vertices per block, 256 threads = 64 j-lanes x 4 vert-groups (8 verts).
// Each thread: layer1 8 verts x 2 j-cols; layer2 8 verts x 1 j-col.
// LDS reads are wave-uniform address -> broadcast, conflict-free.
// ---------------------------------------------------------------------------
#define VPB 32
__global__ __launch_bounds__(256) void
mlp_kernel(const float* __restrict__ x, const float* __restrict__ W1,
           const float* __restrict__ b1, const float* __restrict__ W2,
           const float* __restrict__ b2, float* __restrict__ h) {
    __shared__ float xs[VPB][C_IN];    // 32 KB
    __shared__ float mid[VPB][C_MID];  // 16 KB
    const int t  = threadIdx.x;
    const int v0 = blockIdx.x * VPB;
    const int j0 = t & 63;
    const int vbase = (t >> 6) * 8;

    // stage 32 x-rows as float4 (coalesced 1KB/wave)
    {
        const float* xp = x + (size_t)v0 * C_IN;
#pragma unroll
        for (int it = 0; it < 8; ++it) {
            const int idx = it * 256 + t;       // float4 index
            const int row = idx >> 6;
            const int c4  = (idx & 63) * 4;
            *(float4*)&xs[row][c4] = *(const float4*)&xp[(size_t)row * C_IN + c4];
        }
    }
    __syncthreads();

    {   // layer 1
        float acc0[8], acc1[8];
        const float bA = b1[j0], bB = b1[j0 + 64];
#pragma unroll
        for (int i = 0; i < 8; ++i) { acc0[i] = bA; acc1[i] = bB; }
        for (int k = 0; k < C_IN; k += 4) {
            float4 xv[8];
#pragma unroll
            for (int i = 0; i < 8; ++i)
                xv[i] = *(const float4*)&xs[vbase + i][k];
#pragma unroll
            for (int kk = 0; kk < 4; ++kk) {
                const float w0 = W1[(k + kk) * C_MID + j0];
                const float w1 = W1[(k + kk) * C_MID + j0 + 64];
#pragma unroll
                for (int i = 0; i < 8; ++i) {
                    const float xvv = kk == 0 ? xv[i].x : kk == 1 ? xv[i].y
                                   : kk == 2 ? xv[i].z : xv[i].w;
                    acc0[i] += xvv * w0;
                    acc1[i] += xvv * w1;
                }
            }
        }
#pragma unroll
        for (int i = 0; i < 8; ++i) {
            const float a = acc0[i], b = acc1[i];
            mid[vbase + i][j0]      = a > 0.f ? a : NEG * a;
            mid[vbase + i][j0 + 64] = b > 0.f ? b : NEG * b;
        }
    }
    __syncthreads();

    {   // layer 2
        float acc[8];
        const float bias = b2[j0];
#pragma unroll
        for (int i = 0; i < 8; ++i) acc[i] = bias;
        for (int k = 0; k < C_MID; k += 4) {
            float4 xv[8];
#pragma unroll
            for (int i = 0; i < 8; ++i)
                xv[i] = *(const float4*)&mid[vbase + i][k];
#pragma unroll
            for (int kk = 0; kk < 4; ++kk) {
                const float w0 = W2[(k + kk) * C_OUT + j0];
#pragma unroll
                for (int i = 0; i < 8; ++i) {
                    const float xvv = kk == 0 ? xv[i].x : kk == 1 ? xv[i].y
                                   : kk == 2 ? xv[i].z : xv[i].w;
                    acc[i] += xvv * w0;
                }
            }
        }
#pragma unroll
        for (int i = 0; i < 8; ++i)
            h[(size_t)(v0 + vbase + i) * C_OUT + j0] = acc[i];
    }
}

// ---------------------------------------------------------------------------
// CSR build: count degrees for all three groupings in one pass.
// ---------------------------------------------------------------------------
__global__ void count_kernel(const int* __restrict__ hg_v, const int* __restrict__ hg_e,
                             const int* __restrict__ g_dst,
                             int* __restrict__ deg_e, int* __restrict__ deg_vhg,
                             int* __restrict__ deg_vg) {
    const int i = blockIdx.x * blockDim.x + threadIdx.x;
    if (i >= N_INC) return;
    atomicAdd(&deg_e[hg_e[i]], 1);
    atomicAdd(&deg_vhg[hg_v[i]], 1);
    atomicAdd(&deg_vg[g_dst[i]], 1);
}

// Three independent single-block exclusive scans in ONE dispatch (3 blocks).
__global__ __launch_bounds__(1024) void
scan3_kernel(const int* __restrict__ deg_e,   int* __restrict__ off_e,
             const int* __restrict__ deg_vhg, int* __restrict__ off_vhg,
             const int* __restrict__ deg_vg,  int* __restrict__ off_vg) {
    __shared__ int sums[1024];
    const int* cnt; int* off; int n;
    if (blockIdx.x == 0)      { cnt = deg_e;   off = off_e;   n = N_HGE;   }
    else if (blockIdx.x == 1) { cnt = deg_vhg; off = off_vhg; n = N_VERTS; }
    else                      { cnt = deg_vg;  off = off_vg;  n = N_VERTS; }

    const int t = threadIdx.x;
    const int chunk = (n + 1023) / 1024;
    const int lo = t * chunk;
    const int hi = min(lo + chunk, n);
    int s = 0;
    for (int i = lo; i < hi; ++i) s += cnt[i];
    sums[t] = s;
    __syncthreads();
    for (int d = 1; d < 1024; d <<= 1) {
        int v = (t >= d) ? sums[t - d] : 0;
        __syncthreads();
        sums[t] += v;
        __syncthreads();
    }
    int run = (t > 0) ? sums[t - 1] : 0;
    for (int i = lo; i < hi; ++i) { off[i] = run; run += cnt[i]; }
}

// ---------------------------------------------------------------------------
// Fill adjacency slots with XCD-range bucketing.
// Block b: dst range r = b & 7, pair chunk = b >> 3. Each range's active slot
// regions (~2.4 MB) fit in one XCD's 4 MB L2 -> slot lines accumulate all
// their writes before a single eviction (kills the 16x write amplification).
// ---------------------------------------------------------------------------
#define FILL_PAIRS 2048   // pairs per block (256 threads x 8)
#define ERANGE (N_HGE / 8)
#define VRANGE (N_VERTS / 8)
__global__ __launch_bounds__(256) void
fill_kernel(const int* __restrict__ hg_v, const int* __restrict__ hg_e,
            const int* __restrict__ g_src, const int* __restrict__ g_dst,
            const int* __restrict__ off_e, int* __restrict__ cur_e,
            int* __restrict__ slot_e,
            const int* __restrict__ off_vhg, int* __restrict__ cur_vhg,
            int* __restrict__ slot_vhg,
            const int* __restrict__ off_vg, int* __restrict__ cur_vg,
            int* __restrict__ slot_vg) {
    const int r     = blockIdx.x & 7;
    const int base  = (blockIdx.x >> 3) * FILL_PAIRS + threadIdx.x;
    const int elo = r * ERANGE, ehi = elo + ERANGE;
    const int vlo = r * VRANGE, vhi = vlo + VRANGE;
#pragma unroll
    for (int p = 0; p < 8; ++p) {
        const int i = base + p * 256;
        if (i >= N_INC) break;
        const int v = hg_v[i], e = hg_e[i];
        if (e >= elo && e < ehi) {
            const int pos = off_e[e] + atomicAdd(&cur_e[e], 1);
            slot_e[pos] = v;
        }
        if (v >= vlo && v < vhi) {
            const int pos = off_vhg[v] + atomicAdd(&cur_vhg[v], 1);
            slot_vhg[pos] = e;
        }
        const int s = g_src[i], d = g_dst[i];
        if (d >= vlo && d < vhi) {
            const int pos = off_vg[d] + atomicAdd(&cur_vg[d], 1);
            slot_vg[pos] = s;
        }
    }
}

// ---------------------------------------------------------------------------
// v2e gather: one wave per hyperedge, lane = channel.
// ---------------------------------------------------------------------------
__global__ void gather_e_kernel(const int* __restrict__ slot, const int* __restrict__ off,
                                const int* __restrict__ deg, const float* __restrict__ h,
                                float* __restrict__ e_feat) {
    const int wid  = (blockIdx.x * blockDim.x + threadIdx.x) >> 6;
    const int lane = threadIdx.x & 63;
    if (wid >= N_HGE) return;
    const int n    = deg[wid];
    const int base = off[wid];
    float acc = 0.f;
    int j = 0;
    for (; j + 4 <= n; j += 4) {
        const int v0 = slot[base + j + 0];
        const int v1 = slot[base + j + 1];
        const int v2 = slot[base + j + 2];
        const int v3 = slot[base + j + 3];
        const float r0 = h[(size_t)v0 * C_OUT + lane];
        const float r1 = h[(size_t)v1 * C_OUT + lane];
        const float r2 = h[(size_t)v2 * C_OUT + lane];
        const float r3 = h[(size_t)v3 * C_OUT + lane];
        acc += (r0 + r1) + (r2 + r3);
    }
    for (; j < n; ++j)
        acc += h[(size_t)slot[base + j] * C_OUT + lane];
    e_feat[(size_t)wid * C_OUT + lane] = acc / fmaxf((float)n, 1.f);
}

// ---------------------------------------------------------------------------
// Fused per-vertex: x_hg gather (over e_feat) + x_g gather (over h) +
// softmax-weighted fuse + leaky -> out. One wave per vertex, lane = channel.
// ---------------------------------------------------------------------------
__global__ void vertex_out_kernel(const int* __restrict__ slot_vhg,
                                  const int* __restrict__ off_vhg,
                                  const int* __restrict__ deg_vhg,
                                  const int* __restrict__ slot_vg,
                                  const int* __restrict__ off_vg,
                                  const int* __restrict__ deg_vg,
                                  const float* __restrict__ e_feat,
                                  const float* __restrict__ h,
                                  const float* __restrict__ w,
                                  float* __restrict__ out) {
    const int wid  = (blockIdx.x * blockDim.x + threadIdx.x) >> 6;
    const int lane = threadIdx.x & 63;
    if (wid >= N_VERTS) return;

    float acc_hg = 0.f;
    {
        const int n = deg_vhg[wid];
        const int base = off_vhg[wid];
        int j = 0;
        for (; j + 4 <= n; j += 4) {
            const int e0 = slot_vhg[base + j + 0];
            const int e1 = slot_vhg[base + j + 1];
            const int e2 = slot_vhg[base + j + 2];
            const int e3 = slot_vhg[base + j + 3];
            const float r0 = e_feat[(size_t)e0 * C_OUT + lane];
            const float r1 = e_feat[(size_t)e1 * C_OUT + lane];
            const float r2 = e_feat[(size_t)e2 * C_OUT + lane];
            const float r3 = e_feat[(size_t)e3 * C_OUT + lane];
            acc_hg += (r0 + r1) + (r2 + r3);
        }
        for (; j < n; ++j)
            acc_hg += e_feat[(size_t)slot_vhg[base + j] * C_OUT + lane];
        acc_hg /= fmaxf((float)n, 1.f);
    }

    float acc_g = 0.f;
    {
        const int n = deg_vg[wid];
        const int base = off_vg[wid];
        int j = 0;
        for (; j + 4 <= n; j += 4) {
            const int v0 = slot_vg[base + j + 0];
            const int v1 = slot_vg[base + j + 1];
            const int v2 = slot_vg[base + j + 2];
            const int v3 = slot_vg[base + j + 3];
            const float r0 = h[(size_t)v0 * C_OUT + lane];
            const float r1 = h[(size_t)v1 * C_OUT + lane];
            const float r2 = h[(size_t)v2 * C_OUT + lane];
            const float r3 = h[(size_t)v3 * C_OUT + lane];
            acc_g += (r0 + r1) + (r2 + r3);
        }
        for (; j < n; ++j)
            acc_g += h[(size_t)slot_vg[base + j] * C_OUT + lane];
        acc_g /= fmaxf((float)n, 1.f);
    }

    const float w0 = w[0], w1 = w[1];
    const float m  = fmaxf(w0, w1);
    const float e0 = __expf(w0 - m), e1 = __expf(w1 - m);
    const float sw0 = e0 / (e0 + e1), sw1 = e1 / (e0 + e1);

    const float hv = h[(size_t)wid * C_OUT + lane];
    float o = sw0 * 0.5f * (acc_g + acc_hg) + sw1 * hv;
    o = o > 0.f ? o : NEG * o;
    out[(size_t)wid * C_OUT + lane] = o;
}

// ---------------------------------------------------------------------------
extern "C" void kernel_launch(void* const* d_in, const int* in_sizes, int n_in,
                              void* d_out, int out_size, void* d_ws, size_t ws_size,
                              hipStream_t stream) {
    const float* x    = (const float*)d_in[0];
    const float* W1   = (const float*)d_in[1];
    const float* b1   = (const float*)d_in[2];
    const float* W2   = (const float*)d_in[3];
    const float* b2   = (const float*)d_in[4];
    const float* w    = (const float*)d_in[5];
    const int*  hg_v  = (const int*)d_in[6];
    const int*  hg_e  = (const int*)d_in[7];
    const int*  g_src = (const int*)d_in[8];
    const int*  g_dst = (const int*)d_in[9];
    float* out = (float*)d_out;

    // workspace layout (all 4-byte elems)
    float* h        = (float*)d_ws;                        // N_VERTS*64
    float* e_feat   = h + (size_t)N_VERTS * C_OUT;         // N_HGE*64
    int*   ibase    = (int*)(e_feat + (size_t)N_HGE * C_OUT);
    int* deg_e    = ibase;                 // N_HGE    (zeroed)
    int* cur_e    = deg_e   + N_HGE;       // N_HGE    (zeroed)
    int* deg_vhg  = cur_e   + N_HGE;       // N_VERTS  (zeroed)
    int* cur_vhg  = deg_vhg + N_VERTS;     // N_VERTS  (zeroed)
    int* deg_vg   = cur_vhg + N_VERTS;     // N_VERTS  (zeroed)
    int* cur_vg   = deg_vg  + N_VERTS;     // N_VERTS  (zeroed)
    int* off_e    = cur_vg  + N_VERTS;     // N_HGE
    int* off_vhg  = off_e   + N_HGE;       // N_VERTS
    int* off_vg   = off_vhg + N_VERTS;     // N_VERTS
    int* slot_e   = off_vg  + N_VERTS;     // N_INC
    int* slot_vhg = slot_e  + N_INC;       // N_INC
    int* slot_vg  = slot_vhg + N_INC;      // N_EDGES

    const size_t zero_elems = 2 * (size_t)N_HGE + 4 * (size_t)N_VERTS;
    hipMemsetAsync(ibase, 0, zero_elems * sizeof(int), stream);

    // CSR build
    const int pair_blocks = (N_INC + 255) / 256;
    count_kernel<<<pair_blocks, 256, 0, stream>>>(hg_v, hg_e, g_dst,
                                                  deg_e, deg_vhg, deg_vg);
    scan3_kernel<<<3, 1024, 0, stream>>>(deg_e, off_e, deg_vhg, off_vhg,
                                         deg_vg, off_vg);
    const int fill_chunks = (N_INC + FILL_PAIRS - 1) / FILL_PAIRS;
    fill_kernel<<<fill_chunks * 8, 256, 0, stream>>>(hg_v, hg_e, g_src, g_dst,
                                                     off_e, cur_e, slot_e,
                                                     off_vhg, cur_vhg, slot_vhg,
                                                     off_vg, cur_vg, slot_vg);

    // MLP
    mlp_kernel<<<N_VERTS / VPB, 256, 0, stream>>>(x, W1, b1, W2, b2, h);

    // v2e gather
    const int ge_blocks = (int)(((size_t)N_HGE * 64 + 255) / 256);
    gather_e_kernel<<<ge_blocks, 256, 0, stream>>>(slot_e, off_e, deg_e, h, e_feat);

    // fused e2v + graph gather + finalize
    const int vo_blocks = (int)(((size_t)N_VERTS * 64 + 255) / 256);
    vertex_out_kernel<<<vo_blocks, 256, 0, stream>>>(slot_vhg, off_vhg, deg_vhg,
                                                     slot_vg, off_vg, deg_vg,
                                                     e_feat, h, w, out);
}